// Round 1
// baseline (113.175 us; speedup 1.0000x reference)
//
#include <hip/hip_runtime.h>

#define BINS 256
#define HWPIX (512 * 512)   // pixels per channel
#define NCH 192             // B*C = 64*3

// ---------------- Pass 1: per-channel 256-bin histogram ----------------
// 32 blocks per channel, 256 threads, 8 x float4 per thread:
// 32 * 256 * 8 * 4 = 262144 pixels = HWPIX. LDS histogram then global atomics.
__global__ __launch_bounds__(256) void hist_kernel(const float* __restrict__ x,
                                                   int* __restrict__ ghist) {
    __shared__ int h[BINS];
    const int t = threadIdx.x;
    h[t] = 0;
    __syncthreads();

    const int ch  = blockIdx.x >> 5;   // /32
    const int blk = blockIdx.x & 31;
    const float4* base = (const float4*)(x + (size_t)ch * HWPIX);
    // 65536 float4 per channel; 2048 per block; 8 per thread (stride 256)
    const int idx0 = blk * 2048 + t;

#pragma unroll
    for (int i = 0; i < 8; ++i) {
        float4 v = base[idx0 + i * 256];
        int b0 = (int)fminf(fmaxf(floorf(v.x * 255.0f), 0.0f), 255.0f);
        int b1 = (int)fminf(fmaxf(floorf(v.y * 255.0f), 0.0f), 255.0f);
        int b2 = (int)fminf(fmaxf(floorf(v.z * 255.0f), 0.0f), 255.0f);
        int b3 = (int)fminf(fmaxf(floorf(v.w * 255.0f), 0.0f), 255.0f);
        atomicAdd(&h[b0], 1);
        atomicAdd(&h[b1], 1);
        atomicAdd(&h[b2], 1);
        atomicAdd(&h[b3], 1);
    }
    __syncthreads();
    atomicAdd(&ghist[ch * BINS + t], h[t]);
}

// ---------------- Pass 2: per-channel LUT (192 blocks x 256 threads) ----------------
__global__ __launch_bounds__(256) void lut_kernel(const int* __restrict__ ghist,
                                                  float* __restrict__ glut) {
    __shared__ int h[BINS];
    __shared__ int cum[BINS];
    __shared__ int red[BINS];
    const int t = threadIdx.x;
    const int ch = blockIdx.x;

    const int hv = ghist[ch * BINS + t];
    h[t]   = hv;
    cum[t] = hv;
    red[t] = (hv > 0) ? t : -1;   // candidate for last nonzero bin
    __syncthreads();

    // max-reduce for last nonzero index
    for (int off = 128; off > 0; off >>= 1) {
        if (t < off) red[t] = max(red[t], red[t + off]);
        __syncthreads();
    }

    // Hillis-Steele inclusive scan for cumsum
    for (int off = 1; off < BINS; off <<= 1) {
        int v = cum[t];
        int a = (t >= off) ? cum[t - off] : 0;
        __syncthreads();
        cum[t] = v + a;
        __syncthreads();
    }

    const int last_idx = red[0];
    const int last = h[last_idx];
    const int step = (HWPIX - last) / 255;   // non-negative

    int lutv;
    if (step == 0) {
        lutv = t;                 // identity channel
    } else if (t == 0) {
        lutv = 0;                 // shifted-right-by-one: first entry is 0
    } else {
        int val = (cum[t - 1] + (step >> 1)) / step;
        lutv = min(max(val, 0), 255);
    }
    // pre-divide so the apply pass matches reference fp32 division exactly
    glut[ch * BINS + t] = (float)lutv / 255.0f;
}

// ---------------- Pass 3: apply LUT ----------------
// 32 blocks per channel, 256 threads, 8 x float4 per thread.
__global__ __launch_bounds__(256) void apply_kernel(const float* __restrict__ x,
                                                    const float* __restrict__ glut,
                                                    float* __restrict__ out) {
    __shared__ float lut[BINS];
    const int t = threadIdx.x;
    const int ch  = blockIdx.x >> 5;
    const int blk = blockIdx.x & 31;
    lut[t] = glut[ch * BINS + t];
    __syncthreads();

    const size_t chbase = (size_t)ch * HWPIX;
    const float4* in4 = (const float4*)(x + chbase);
    float4* out4      = (float4*)(out + chbase);
    const int idx0 = blk * 2048 + t;

#pragma unroll
    for (int i = 0; i < 8; ++i) {
        float4 v = in4[idx0 + i * 256];
        float4 o;
        o.x = lut[(int)fminf(fmaxf(floorf(v.x * 255.0f), 0.0f), 255.0f)];
        o.y = lut[(int)fminf(fmaxf(floorf(v.y * 255.0f), 0.0f), 255.0f)];
        o.z = lut[(int)fminf(fmaxf(floorf(v.z * 255.0f), 0.0f), 255.0f)];
        o.w = lut[(int)fminf(fmaxf(floorf(v.w * 255.0f), 0.0f), 255.0f)];
        out4[idx0 + i * 256] = o;
    }
}

extern "C" void kernel_launch(void* const* d_in, const int* in_sizes, int n_in,
                              void* d_out, int out_size, void* d_ws, size_t ws_size,
                              hipStream_t stream) {
    const float* x = (const float*)d_in[0];
    float* out = (float*)d_out;

    int*   ghist = (int*)d_ws;
    float* glut  = (float*)((char*)d_ws + (size_t)NCH * BINS * sizeof(int));

    hipMemsetAsync(d_ws, 0, (size_t)NCH * BINS * sizeof(int), stream);
    hist_kernel <<<NCH * 32, 256, 0, stream>>>(x, ghist);
    lut_kernel  <<<NCH,      256, 0, stream>>>(ghist, glut);
    apply_kernel<<<NCH * 32, 256, 0, stream>>>(x, glut, out);
}

// Round 3
// 111.667 us; speedup vs baseline: 1.0135x; 1.0135x over previous
//
#include <hip/hip_runtime.h>

#define BINS 256
#define HWPIX (512 * 512)   // pixels per channel
#define NCH 192             // B*C = 64*3
#define BPC 32              // blocks per channel
// per block: 256 threads x 8 float4 = 8192 px; 32 blocks x 8192 = 262144 = HWPIX

// Workspace layout: [ ghist: NCH*BINS int ][ staged u8 (as u32): NCH*HWPIX/4 u32 ]
#define GHIST_BYTES ((size_t)NCH * BINS * sizeof(int))
#define STAGED_WORDS ((size_t)NCH * (HWPIX / 4))
#define WS_NEEDED (GHIST_BYTES + STAGED_WORDS * sizeof(unsigned int))

// ---------------- Pass 1: histogram + quantize + stage packed u8 ----------------
__global__ __launch_bounds__(256) void hist_stage_kernel(const float* __restrict__ x,
                                                         int* __restrict__ ghist,
                                                         unsigned int* __restrict__ staged) {
    __shared__ int h[BINS];
    const int t = threadIdx.x;
    h[t] = 0;
    __syncthreads();

    const int ch  = blockIdx.x >> 5;
    const int blk = blockIdx.x & 31;
    const float4* in4 = (const float4*)(x + (size_t)ch * HWPIX);
    unsigned int* st  = staged + (size_t)ch * (HWPIX / 4);
    const int idx0 = blk * 2048 + t;

#pragma unroll
    for (int i = 0; i < 8; ++i) {
        const int k = idx0 + i * 256;
        float4 v = in4[k];
        int b0 = (int)fminf(fmaxf(floorf(v.x * 255.0f), 0.0f), 255.0f);
        int b1 = (int)fminf(fmaxf(floorf(v.y * 255.0f), 0.0f), 255.0f);
        int b2 = (int)fminf(fmaxf(floorf(v.z * 255.0f), 0.0f), 255.0f);
        int b3 = (int)fminf(fmaxf(floorf(v.w * 255.0f), 0.0f), 255.0f);
        st[k] = (unsigned int)b0 | ((unsigned int)b1 << 8) |
                ((unsigned int)b2 << 16) | ((unsigned int)b3 << 24);
        atomicAdd(&h[b0], 1);
        atomicAdd(&h[b1], 1);
        atomicAdd(&h[b2], 1);
        atomicAdd(&h[b3], 1);
    }
    __syncthreads();
    atomicAdd(&ghist[ch * BINS + t], h[t]);
}

// ---------------- Pass 1 fallback (no staging) ----------------
__global__ __launch_bounds__(256) void hist_kernel(const float* __restrict__ x,
                                                   int* __restrict__ ghist) {
    __shared__ int h[BINS];
    const int t = threadIdx.x;
    h[t] = 0;
    __syncthreads();

    const int ch  = blockIdx.x >> 5;
    const int blk = blockIdx.x & 31;
    const float4* in4 = (const float4*)(x + (size_t)ch * HWPIX);
    const int idx0 = blk * 2048 + t;

#pragma unroll
    for (int i = 0; i < 8; ++i) {
        float4 v = in4[idx0 + i * 256];
        int b0 = (int)fminf(fmaxf(floorf(v.x * 255.0f), 0.0f), 255.0f);
        int b1 = (int)fminf(fmaxf(floorf(v.y * 255.0f), 0.0f), 255.0f);
        int b2 = (int)fminf(fmaxf(floorf(v.z * 255.0f), 0.0f), 255.0f);
        int b3 = (int)fminf(fmaxf(floorf(v.w * 255.0f), 0.0f), 255.0f);
        atomicAdd(&h[b0], 1);
        atomicAdd(&h[b1], 1);
        atomicAdd(&h[b2], 1);
        atomicAdd(&h[b3], 1);
    }
    __syncthreads();
    atomicAdd(&ghist[ch * BINS + t], h[t]);
}

// ---------------- Pass 2: per-channel LUT (192 blocks x 256 threads) ----------------
__global__ __launch_bounds__(256) void lut_kernel(const int* __restrict__ ghist,
                                                  float* __restrict__ glut) {
    __shared__ int h[BINS];
    __shared__ int cum[BINS];
    __shared__ int red[BINS];
    const int t = threadIdx.x;
    const int ch = blockIdx.x;

    const int hv = ghist[ch * BINS + t];
    h[t]   = hv;
    cum[t] = hv;
    red[t] = (hv > 0) ? t : -1;
    __syncthreads();

    for (int off = 128; off > 0; off >>= 1) {       // last nonzero bin index
        if (t < off) red[t] = max(red[t], red[t + off]);
        __syncthreads();
    }
    for (int off = 1; off < BINS; off <<= 1) {      // inclusive scan
        int v = cum[t];
        int a = (t >= off) ? cum[t - off] : 0;
        __syncthreads();
        cum[t] = v + a;
        __syncthreads();
    }

    const int last = h[red[0]];
    const int step = (HWPIX - last) / 255;

    int lutv;
    if (step == 0) {
        lutv = t;                                   // identity channel
    } else if (t == 0) {
        lutv = 0;
    } else {
        int val = (cum[t - 1] + (step >> 1)) / step;
        lutv = min(max(val, 0), 255);
    }
    glut[ch * BINS + t] = (float)lutv / 255.0f;     // pre-divide (bit-exact w/ ref)
}

// ---------------- Pass 3: apply from staged u8 ----------------
__global__ __launch_bounds__(256) void apply_staged_kernel(const unsigned int* __restrict__ staged,
                                                           const float* __restrict__ glut,
                                                           float* __restrict__ out) {
    __shared__ float lut[BINS];
    const int t = threadIdx.x;
    const int ch  = blockIdx.x >> 5;
    const int blk = blockIdx.x & 31;
    lut[t] = glut[ch * BINS + t];
    __syncthreads();

    const unsigned int* st = staged + (size_t)ch * (HWPIX / 4);
    float4* out4 = (float4*)(out + (size_t)ch * HWPIX);
    const int idx0 = blk * 2048 + t;

#pragma unroll
    for (int i = 0; i < 8; ++i) {
        const int k = idx0 + i * 256;
        unsigned int p = st[k];
        float4 o;
        o.x = lut[p & 255u];
        o.y = lut[(p >> 8) & 255u];
        o.z = lut[(p >> 16) & 255u];
        o.w = lut[p >> 24];
        out4[k] = o;
    }
}

// ---------------- Pass 3 fallback: apply from fp32 input ----------------
__global__ __launch_bounds__(256) void apply_f32_kernel(const float* __restrict__ x,
                                                        const float* __restrict__ glut,
                                                        float* __restrict__ out) {
    __shared__ float lut[BINS];
    const int t = threadIdx.x;
    const int ch  = blockIdx.x >> 5;
    const int blk = blockIdx.x & 31;
    lut[t] = glut[ch * BINS + t];
    __syncthreads();

    const size_t chbase = (size_t)ch * HWPIX;
    const float4* in4 = (const float4*)(x + chbase);
    float4* out4      = (float4*)(out + chbase);
    const int idx0 = blk * 2048 + t;

#pragma unroll
    for (int i = 0; i < 8; ++i) {
        float4 v = in4[idx0 + i * 256];
        float4 o;
        o.x = lut[(int)fminf(fmaxf(floorf(v.x * 255.0f), 0.0f), 255.0f)];
        o.y = lut[(int)fminf(fmaxf(floorf(v.y * 255.0f), 0.0f), 255.0f)];
        o.z = lut[(int)fminf(fmaxf(floorf(v.z * 255.0f), 0.0f), 255.0f)];
        o.w = lut[(int)fminf(fmaxf(floorf(v.w * 255.0f), 0.0f), 255.0f)];
        out4[idx0 + i * 256] = o;
    }
}

extern "C" void kernel_launch(void* const* d_in, const int* in_sizes, int n_in,
                              void* d_out, int out_size, void* d_ws, size_t ws_size,
                              hipStream_t stream) {
    const float* x = (const float*)d_in[0];
    float* out = (float*)d_out;

    int* ghist = (int*)d_ws;
    // glut lives right after ghist when staging is unavailable; when staging
    // is available, put glut after the staged buffer.
    hipMemsetAsync(d_ws, 0, GHIST_BYTES, stream);

    if (ws_size >= WS_NEEDED + (size_t)NCH * BINS * sizeof(float)) {
        unsigned int* staged = (unsigned int*)((char*)d_ws + GHIST_BYTES);
        float* glut = (float*)((char*)d_ws + WS_NEEDED);
        hist_stage_kernel  <<<NCH * BPC, 256, 0, stream>>>(x, ghist, staged);
        lut_kernel         <<<NCH,       256, 0, stream>>>(ghist, glut);
        apply_staged_kernel<<<NCH * BPC, 256, 0, stream>>>(staged, glut, out);
    } else {
        float* glut = (float*)((char*)d_ws + GHIST_BYTES);
        hist_kernel        <<<NCH * BPC, 256, 0, stream>>>(x, ghist);
        lut_kernel         <<<NCH,       256, 0, stream>>>(ghist, glut);
        apply_f32_kernel   <<<NCH * BPC, 256, 0, stream>>>(x, glut, out);
    }
}